// Round 1
// baseline (957.931 us; speedup 1.0000x reference)
//
#include <hip/hip_runtime.h>
#include <hip/hip_bf16.h>

// CPCA_Weighted: T=256 N=8 H=512 K=16 A=4, 7 actions, P_SUB=0.1, LOSS_FACTOR=0.1
#define T_DIM 256
#define N_DIM 8
#define H_DIM 512
#define KK    16
#define NSEQ  2048
#define G3H   1536

typedef __attribute__((ext_vector_type(8))) short bf16x8;
typedef __attribute__((ext_vector_type(4))) float f32x4;

__device__ __forceinline__ unsigned short f2b(float x) {
  unsigned u = __float_as_uint(x);
  unsigned r = (u + 0x7FFFu + ((u >> 16) & 1u)) >> 16;   // RNE
  return (unsigned short)r;
}

// JAX threefry2x32 (20 rounds)
__device__ __forceinline__ void tf2x32(unsigned k0, unsigned k1, unsigned x0, unsigned x1,
                                       unsigned &o0, unsigned &o1) {
  unsigned ks2 = k0 ^ k1 ^ 0x1BD11BDAu;
  x0 += k0; x1 += k1;
#define TFR(R) { x0 += x1; x1 = (x1 << R) | (x1 >> (32 - R)); x1 ^= x0; }
  TFR(13) TFR(15) TFR(26) TFR(6)   x0 += k1;  x1 += ks2 + 1u;
  TFR(17) TFR(29) TFR(16) TFR(24)  x0 += ks2; x1 += k0 + 2u;
  TFR(13) TFR(15) TFR(26) TFR(6)   x0 += k0;  x1 += k1 + 3u;
  TFR(17) TFR(29) TFR(16) TFR(24)  x0 += k1;  x1 += ks2 + 4u;
  TFR(13) TFR(15) TFR(26) TFR(6)   x0 += ks2; x1 += k0 + 5u;
#undef TFR
  o0 = x0; o1 = x1;
}

// ---------------- prep1: weight converts, gi_table, projP, RNG/valid masks ----
__global__ void prep1(const float* __restrict__ W_hh, const float* __restrict__ W1,
                      const float* __restrict__ emb,  const float* __restrict__ W_ih,
                      const float* __restrict__ b_ih, const float* __restrict__ vision,
                      const int* __restrict__ env_zeros,
                      unsigned short* __restrict__ wB, unsigned short* __restrict__ wQ,
                      float* __restrict__ gi_tab, float* __restrict__ projP,
                      unsigned char* __restrict__ maskb, float* __restrict__ accum) {
  int b = blockIdx.x, tid = threadIdx.x;
  if (b < 768) {                               // W_hh -> bf16, 4 elems/thread
    int g = (b * 256 + tid) * 4;
    float4 v = *(const float4*)(W_hh + g);
    ushort4 o; o.x = f2b(v.x); o.y = f2b(v.y); o.z = f2b(v.z); o.w = f2b(v.w);
    *(ushort4*)(wB + g) = o;
  } else if (b < 832) {                        // W1b -> bf16  [32][512]
    int e = (b - 768) * 256 + tid;
    int f = e >> 9, k = e & 511;
    wQ[e] = f2b(W1[f * 1024 + 512 + k]);
  } else if (b < 880) {                        // gi_table [8][1536]; row7 = pad (x=0)
    int e = (b - 832) * 256 + tid;
    int a = e / 1536, c = e - a * 1536;
    float s = b_ih[c];
    if (a < 7) {
      #pragma unroll
      for (int k = 0; k < 4; ++k) s += emb[a * 4 + k] * W_ih[c * 4 + k];
    }
    gi_tab[e] = s;
    if (e < 4) accum[e] = 0.f;                 // zero loss accumulators (ws is poisoned)
  } else if (b < 1136) {                       // projP[s][f] = vision[s] . W1a[f]
    int e = (b - 880) * 256 + tid;
    int s = e >> 5, f = e & 31;
    const float4* vr = (const float4*)(vision + (size_t)s * 512);
    const float4* wr = (const float4*)(W1 + (size_t)f * 1024);
    float acc = 0.f;
    for (int i = 0; i < 128; ++i) {
      float4 a = vr[i], w = wr[i];
      acc += a.x * w.x + a.y * w.y + a.z * w.z + a.w * w.w;
    }
    projP[e] = acc;
  } else {                                     // masks: legacy JAX threefry
    int i = (b - 1136) * 256 + tid;            // i in [0,16384)
    unsigned a0, b0, a1, b1_;
    tf2x32(0u, 42u, 0u, 2u, a0, b0);           // split(key(42)): pairs (0,2),(1,3)
    tf2x32(0u, 42u, 1u, 3u, a1, b1_);          // k1=(a0,a1), k2=(b0,b1_)
    unsigned p0, p1, n0, n1;
    tf2x32(a0, a1, (unsigned)i, (unsigned)(i + 16384), p0, p1);
    tf2x32(b0, b1_, (unsigned)i, (unsigned)(i + 16384), n0, n1);
    #pragma unroll
    for (int h = 0; h < 2; ++h) {
      int f = i + h * 16384;
      unsigned pw = h ? p1 : p0, nw = h ? n1 : n0;
      int t = f >> 7, j = (f >> 3) & 15, nn = f & 7;
      int ok = (t + j < T_DIM - 1);
      if (ok) {
        int lo = t + 1, hi = t + j + 1, hit = 0;
        #pragma unroll
        for (int q = 0; q < 4; ++q) { int z = env_zeros[nn * 4 + q]; hit |= (z >= lo && z <= hi); }
        ok = !hit;
      }
      unsigned sp = ((pw >> 9) < 0xCCCCDu) ? 1u : 0u;   // u<0.1  (mantissa compare)
      unsigned sn = ((nw >> 9) < 0xCCCCDu) ? 2u : 0u;
      maskb[f] = ok ? (unsigned char)(sp | sn) : (unsigned char)0;
    }
  }
}

// ---------------- prep2: K-extension tile (one-hot gi for r,z gates + biases) --
__global__ void prep2(const float* __restrict__ gi_tab, const float* __restrict__ b_hh,
                      unsigned short* __restrict__ extb) {
  int e = blockIdx.x * 256 + threadIdx.x;      // [1536][32]
  if (e >= 1536 * 32) return;
  int c = e >> 5, kp = e & 31;
  float v = 0.f;
  if (kp < 8) { if (c < 1024) v = gi_tab[kp * 1536 + c]; }   // r,z gates get gi
  else if (kp == 8) v = b_hh[c];                              // always-on bias row
  extb[e] = f2b(v);
}

#define MFMA16(A, B, C) __builtin_amdgcn_mfma_f32_16x16x32_bf16(A, B, C, 0, 0, 0)

// ---------------- main: persistent GRU + fused classifier/loss -----------------
__global__ __launch_bounds__(256, 1) void gru_main(
    const float* __restrict__ belief, const int* __restrict__ actions,
    const int* __restrict__ neg_inds,
    const float* __restrict__ b1, const float* __restrict__ W2, const float* __restrict__ b2,
    const unsigned short* __restrict__ wB, const unsigned short* __restrict__ extb,
    const unsigned short* __restrict__ wQ, const float* __restrict__ gi_tab,
    const float* __restrict__ projP, const unsigned char* __restrict__ maskb,
    float* __restrict__ accum) {
  __shared__ float hsF[16][516];               // fp32 state, stride 516: conflict-free
  __shared__ unsigned short hsB[16][520];      // bf16 state, stride 520: 16B-aligned frags

  const int tid  = threadIdx.x;
  const int w    = tid >> 6;                   // wave 0..3: owns hidden cols [128w,128w+128)
  const int lane = tid & 63;
  const int col0 = lane & 15;                  // MFMA n-index / A m-index
  const int quad = lane >> 4;
  const int s0   = blockIdx.x << 4;            // 16 sequences per wg

  for (int it = tid; it < 16 * 128; it += 256) {
    int row = it >> 7, c4 = it & 127;
    float4 v = *(const float4*)(belief + ((size_t)(s0 + row) << 9) + (c4 << 2));
    *(float4*)&hsF[row][c4 << 2] = v;
    ushort4 o; o.x = f2b(v.x); o.y = f2b(v.y); o.z = f2b(v.z); o.w = f2b(v.w);
    *(ushort4*)&hsB[row][c4 << 2] = o;
  }

  const float b1v0 = b1[col0], b1v1 = b1[col0 + 16];
  const float w2v0 = W2[col0], w2v1 = W2[col0 + 16];
  const float b2v  = b2[0];
  const int gsl = s0 + col0;                   // this lane's A-row sequence
  const int tl  = gsl >> 3, nnl = gsl & 7;

  float sumP = 0.f, cntP = 0.f, sumN = 0.f, cntN = 0.f;
  bf16x8 a[16];

  __syncthreads();

  for (int j = 0; j <= KK; ++j) {
    // A-fragments of h_j (bf16) — also serve as query fragments for step j-1
    #pragma unroll
    for (int kt = 0; kt < 16; ++kt)
      a[kt] = *(const bf16x8*)&hsB[col0][kt * 32 + quad * 8];

    if (j > 0) {                               // classifier + loss for step j-1
      const int jq = j - 1;
      f32x4 t0 = {0.f, 0.f, 0.f, 0.f}, t1 = {0.f, 0.f, 0.f, 0.f};
      const unsigned short* q0p = wQ + ((size_t)col0 << 9) + (quad << 3);
      const unsigned short* q1p = wQ + ((size_t)(col0 + 16) << 9) + (quad << 3);
      #pragma unroll
      for (int kt = 0; kt < 16; ++kt) {
        bf16x8 bq0 = *(const bf16x8*)(q0p + (kt << 5));
        bf16x8 bq1 = *(const bf16x8*)(q1p + (kt << 5));
        t0 = MFMA16(a[kt], bq0, t0);
        t1 = MFMA16(a[kt], bq1, t1);
      }
      float wj = (jq == 0) ? 5.f : (jq == 1) ? 4.f : (jq < 4) ? 3.f : (jq < 8) ? 2.f : 1.f;
      #pragma unroll
      for (int r = 0; r < 4; ++r) {
        int m = (quad << 2) + r;
        int gs = s0 + m;
        int trow = gs >> 3, nn = gs & 7;
        unsigned mb = maskb[(trow << 7) + (jq << 3) + nn];   // uniform across quad
        if (mb) {
          int sp = gs + ((jq + 1) << 3);                     // partner row t+j+1
          float pp0 = projP[(sp << 5) + col0];
          float pp1 = projP[(sp << 5) + 16 + col0];
          int ni = neg_inds[sp];
          float pn0 = projP[(ni << 5) + col0];
          float pn1 = projP[(ni << 5) + 16 + col0];
          float a0v = t0[r] + b1v0, a1v = t1[r] + b1v1;
          float pl = fmaxf(a0v + pp0, 0.f) * w2v0 + fmaxf(a1v + pp1, 0.f) * w2v1;
          float nl = fmaxf(a0v + pn0, 0.f) * w2v0 + fmaxf(a1v + pn1, 0.f) * w2v1;
          #pragma unroll
          for (int d = 1; d < 16; d <<= 1) {
            pl += __shfl_xor(pl, d, 64);
            nl += __shfl_xor(nl, d, 64);
          }
          if (col0 == 0 && quad == w) {        // each wave commits its quad's rows
            if (mb & 1u) {
              float x = -(pl + b2v);
              sumP += wj * (fmaxf(x, 0.f) + __logf(1.f + __expf(-fabsf(x))));
              cntP += 1.f;
            }
            if (mb & 2u) {
              float x = (nl + b2v);
              sumN += wj * (fmaxf(x, 0.f) + __logf(1.f + __expf(-fabsf(x))));
              cntN += 1.f;
            }
          }
        }
      }
    }
    if (j == KK) break;
    __syncthreads();                           // frag reads done before h updates

    // one-hot K-extension A fragment (injects gi for r,z + bias row)
    int tj = tl + j;
    int aidx = (tj < T_DIM) ? actions[(tj << 3) + nnl] : 7;
    bf16x8 aext = {0, 0, 0, 0, 0, 0, 0, 0};
    const short oneb = (short)0x3F80;
    if (quad == 0) {
      #pragma unroll
      for (int i = 0; i < 8; ++i) aext[i] = (aidx == i) ? oneb : (short)0;
    } else if (quad == 1) aext[0] = oneb;

    for (int ct = 0; ct < 8; ++ct) {
      int hcol = (w << 7) + (ct << 4);
      int rowR = hcol + col0, rowZ = 512 + hcol + col0, rowN = 1024 + hcol + col0;
      const unsigned short* pR = wB + ((size_t)rowR << 9) + (quad << 3);
      const unsigned short* pZ = wB + ((size_t)rowZ << 9) + (quad << 3);
      const unsigned short* pN = wB + ((size_t)rowN << 9) + (quad << 3);
      f32x4 accR = {0.f, 0.f, 0.f, 0.f}, accZ = accR, accN = accR;
      bf16x8 bR = *(const bf16x8*)pR;
      bf16x8 bZ = *(const bf16x8*)pZ;
      bf16x8 bN = *(const bf16x8*)pN;
      #pragma unroll
      for (int kt = 0; kt < 16; ++kt) {
        bf16x8 nR, nZ, nN;
        if (kt < 15) {
          nR = *(const bf16x8*)(pR + ((kt + 1) << 5));
          nZ = *(const bf16x8*)(pZ + ((kt + 1) << 5));
          nN = *(const bf16x8*)(pN + ((kt + 1) << 5));
        } else {
          nR = *(const bf16x8*)(extb + ((size_t)rowR << 5) + (quad << 3));
          nZ = *(const bf16x8*)(extb + ((size_t)rowZ << 5) + (quad << 3));
          nN = *(const bf16x8*)(extb + ((size_t)rowN << 5) + (quad << 3));
        }
        accR = MFMA16(a[kt], bR, accR);
        accZ = MFMA16(a[kt], bZ, accZ);
        accN = MFMA16(a[kt], bN, accN);
        bR = nR; bZ = nZ; bN = nN;
      }
      accR = MFMA16(aext, bR, accR);           // gi(r,z) + b_hh; accN gets b_hh only
      accZ = MFMA16(aext, bZ, accZ);
      accN = MFMA16(aext, bN, accN);

      #pragma unroll
      for (int r = 0; r < 4; ++r) {
        int m = (quad << 2) + r;
        int ai = __shfl(aidx, m, 64);
        float gin = gi_tab[ai * 1536 + 1024 + hcol + col0];  // i_n (kept out of r*h_n)
        float hp  = hsF[m][hcol + col0];
        float rg = 1.f / (1.f + __expf(-accR[r]));
        float zg = 1.f / (1.f + __expf(-accZ[r]));
        float pre = gin + rg * accN[r];
        float cand = 1.f - 2.f / (1.f + __expf(2.f * pre));  // tanh
        float hn = (1.f - zg) * cand + zg * hp;
        hsF[m][hcol + col0] = hn;
        hsB[m][hcol + col0] = f2b(hn);
      }
    }
    __syncthreads();                           // h_{j+1} visible to all waves
  }

  if (col0 == 0 && quad == w) {
    atomicAdd(&accum[0], sumP); atomicAdd(&accum[1], cntP);
    atomicAdd(&accum[2], sumN); atomicAdd(&accum[3], cntN);
  }
}

__global__ void fin(const float* __restrict__ accum, float* __restrict__ out) {
  out[0] = (accum[0] / fmaxf(accum[1], 1.f) + accum[2] / fmaxf(accum[3], 1.f)) * 0.1f;
}

extern "C" void kernel_launch(void* const* d_in, const int* in_sizes, int n_in,
                              void* d_out, int out_size, void* d_ws, size_t ws_size,
                              hipStream_t stream) {
  const float* vision  = (const float*)d_in[0];
  const float* belief  = (const float*)d_in[1];
  const int*   actions = (const int*)d_in[2];
  const int*   envz    = (const int*)d_in[3];
  const int*   negi    = (const int*)d_in[4];
  const float* emb     = (const float*)d_in[5];
  const float* W_ih    = (const float*)d_in[6];
  const float* W_hh    = (const float*)d_in[7];
  const float* b_ih    = (const float*)d_in[8];
  const float* b_hh    = (const float*)d_in[9];
  const float* W1      = (const float*)d_in[10];
  const float* b1      = (const float*)d_in[11];
  const float* W2      = (const float*)d_in[12];
  const float* b2      = (const float*)d_in[13];

  char* ws = (char*)d_ws;
  float*          accum  = (float*)(ws + 0);            // 4 floats
  float*          gi_tab = (float*)(ws + 256);          // 8*1536*4   = 49152
  unsigned short* extb   = (unsigned short*)(ws + 49664);   // 1536*32*2 = 98304
  unsigned short* wB     = (unsigned short*)(ws + 147968);  // 1536*512*2 = 1572864
  unsigned short* wQ     = (unsigned short*)(ws + 1720832); // 32*512*2  = 32768
  float*          projP  = (float*)(ws + 1753600);      // 2048*32*4 = 262144
  unsigned char*  maskb  = (unsigned char*)(ws + 2015744);  // 32768

  prep1<<<1200, 256, 0, stream>>>(W_hh, W1, emb, W_ih, b_ih, vision, envz,
                                  wB, wQ, gi_tab, projP, maskb, accum);
  prep2<<<192, 256, 0, stream>>>(gi_tab, b_hh, extb);
  gru_main<<<128, 256, 0, stream>>>(belief, actions, negi, b1, W2, b2,
                                    wB, extb, wQ, gi_tab, projP, maskb, accum);
  fin<<<1, 1, 0, stream>>>(accum, (float*)d_out);
}

// Round 2
// 438.002 us; speedup vs baseline: 2.1870x; 2.1870x over previous
//
#include <hip/hip_runtime.h>
#include <hip/hip_bf16.h>

// CPCA_Weighted: T=256 N=8 H=512 K=16 A=4, 7 actions, P_SUB=0.1, LOSS_FACTOR=0.1
#define T_DIM 256
#define KK    16

typedef __attribute__((ext_vector_type(8))) short bf16x8;
typedef __attribute__((ext_vector_type(4))) float f32x4;

#define WBF_SHORTS (32 * 3 * 17 * 512)   // 835584
#define WQF_SHORTS (2 * 16 * 512)        // 16384

__device__ __forceinline__ unsigned short f2b(float x) {
  unsigned u = __float_as_uint(x);
  unsigned r = (u + 0x7FFFu + ((u >> 16) & 1u)) >> 16;   // RNE
  return (unsigned short)r;
}

// JAX threefry2x32 (20 rounds)
__device__ __forceinline__ void tf2x32(unsigned k0, unsigned k1, unsigned x0, unsigned x1,
                                       unsigned &o0, unsigned &o1) {
  unsigned ks2 = k0 ^ k1 ^ 0x1BD11BDAu;
  x0 += k0; x1 += k1;
#define TFR(R) { x0 += x1; x1 = (x1 << R) | (x1 >> (32 - R)); x1 ^= x0; }
  TFR(13) TFR(15) TFR(26) TFR(6)   x0 += k1;  x1 += ks2 + 1u;
  TFR(17) TFR(29) TFR(16) TFR(24)  x0 += ks2; x1 += k0 + 2u;
  TFR(13) TFR(15) TFR(26) TFR(6)   x0 += k0;  x1 += k1 + 3u;
  TFR(17) TFR(29) TFR(16) TFR(24)  x0 += k1;  x1 += ks2 + 4u;
  TFR(13) TFR(15) TFR(26) TFR(6)   x0 += ks2; x1 += k0 + 5u;
#undef TFR
  o0 = x0; o1 = x1;
}

// ---- prep_misc: gin_tab (i_n per action), projP, RNG/valid masks, accum zero --
__global__ void prep_misc(const float* __restrict__ emb, const float* __restrict__ W_ih,
                          const float* __restrict__ b_ih, const float* __restrict__ W1,
                          const float* __restrict__ vision, const int* __restrict__ env_zeros,
                          float* __restrict__ gin_tab, float* __restrict__ projP,
                          unsigned char* __restrict__ maskb, float* __restrict__ accum) {
  int b = blockIdx.x, tid = threadIdx.x;
  if (b < 16) {                                // gin_tab[8][512]: i_n = b_ih_n + emb@W_ih_n
    int e = b * 256 + tid;
    int a = e >> 9, c = e & 511;
    float s = b_ih[1024 + c];
    if (a < 7) {
      #pragma unroll
      for (int k = 0; k < 4; ++k) s += emb[a * 4 + k] * W_ih[(1024 + c) * 4 + k];
    }
    gin_tab[e] = s;
    if (e < 4) accum[e] = 0.f;
  } else if (b < 272) {                        // projP[s][f] = vision[s] . W1a[f]
    int e = (b - 16) * 256 + tid;
    int s = e >> 5, f = e & 31;
    const float4* vr = (const float4*)(vision + (size_t)s * 512);
    const float4* wr = (const float4*)(W1 + (size_t)f * 1024);
    float acc = 0.f;
    for (int i = 0; i < 128; ++i) {
      float4 a = vr[i], w = wr[i];
      acc += a.x * w.x + a.y * w.y + a.z * w.z + a.w * w.w;
    }
    projP[e] = acc;
  } else {                                     // masks: legacy JAX threefry
    int i = (b - 272) * 256 + tid;             // i in [0,16384)
    unsigned a0, b0, a1, b1_;
    tf2x32(0u, 42u, 0u, 2u, a0, b0);           // split(key(42))
    tf2x32(0u, 42u, 1u, 3u, a1, b1_);
    unsigned p0, p1, n0, n1;
    tf2x32(a0, a1, (unsigned)i, (unsigned)(i + 16384), p0, p1);
    tf2x32(b0, b1_, (unsigned)i, (unsigned)(i + 16384), n0, n1);
    #pragma unroll
    for (int h = 0; h < 2; ++h) {
      int f = i + h * 16384;
      unsigned pw = h ? p1 : p0, nw = h ? n1 : n0;
      int t = f >> 7, j = (f >> 3) & 15, nn = f & 7;
      int ok = (t + j < T_DIM - 1);
      if (ok) {
        int lo = t + 1, hi = t + j + 1, hit = 0;
        #pragma unroll
        for (int q = 0; q < 4; ++q) { int z = env_zeros[nn * 4 + q]; hit |= (z >= lo && z <= hi); }
        ok = !hit;
      }
      unsigned sp = ((pw >> 9) < 0xCCCCDu) ? 1u : 0u;   // u<0.1
      unsigned sn = ((nw >> 9) < 0xCCCCDu) ? 2u : 0u;
      maskb[f] = ok ? (unsigned char)(sp | sn) : (unsigned char)0;
    }
  }
}

// ---- prep_w: swizzle W_hh(+ext)/W1b into MFMA-fragment-contiguous streams ----
// wBf layout: frag F = (nt*3+g)*17 + kt; wBf[F*512 + lane*8 + e]
//   kt<16:  W_hh[row(g,nt,col0)][kt*32 + quad*8 + e]
//   kt==16: ext row (gi for r,z one-hot cols, b_hh bias col)
__global__ void prep_w(const float* __restrict__ W_hh, const float* __restrict__ emb,
                       const float* __restrict__ W_ih, const float* __restrict__ b_ih,
                       const float* __restrict__ b_hh, const float* __restrict__ W1,
                       unsigned short* __restrict__ wBf, unsigned short* __restrict__ wQf) {
  int idx = blockIdx.x * 256 + threadIdx.x;
  if (idx < WBF_SHORTS) {
    int within = idx & 511;
    int lane = within >> 3, e = within & 7;
    int F = idx >> 9;
    int kt = F % 17, tg = F / 17;
    int g = tg % 3, nt = tg / 3;
    int col0 = lane & 15, quad = lane >> 4;
    int row = g * 512 + nt * 16 + col0;
    float val;
    if (kt < 16) {
      val = W_hh[(size_t)row * 512 + kt * 32 + quad * 8 + e];
    } else {
      int kp = quad * 8 + e;
      if (kp < 8) {
        if (g < 2) {                           // gi for r,z gates (incl b_ih)
          val = b_ih[row];
          if (kp < 7) {
            #pragma unroll
            for (int k = 0; k < 4; ++k) val += emb[kp * 4 + k] * W_ih[row * 4 + k];
          }
        } else val = 0.f;                      // n-gate: i_n added in epilogue
      } else val = (kp == 8) ? b_hh[row] : 0.f;
    }
    wBf[idx] = f2b(val);
  } else {
    int j2 = idx - WBF_SHORTS;
    if (j2 < WQF_SHORTS) {                     // wQf: frag F = ft*16+kt
      int within = j2 & 511, lane = within >> 3, e = within & 7;
      int F = j2 >> 9, kt = F & 15, ft = F >> 4;
      int col0 = lane & 15, quad = lane >> 4;
      int f = ft * 16 + col0;
      wQf[j2] = f2b(W1[(size_t)f * 1024 + 512 + kt * 32 + quad * 8 + e]);
    }
  }
}

#define MFMA16(A, B, C) __builtin_amdgcn_mfma_f32_16x16x32_bf16(A, B, C, 0, 0, 0)

// ---- main: persistent GRU + fused classifier/loss. 512 thr = 8 waves/wg. ----
// Wave w owns hidden cols [64w, 64w+64) as 4 16-col MFMA N-tiles.
__global__ __launch_bounds__(512, 1) void gru_main(
    const float* __restrict__ belief, const int* __restrict__ actions,
    const int* __restrict__ neg_inds,
    const float* __restrict__ b1, const float* __restrict__ W2, const float* __restrict__ b2,
    const unsigned short* __restrict__ wBf, const unsigned short* __restrict__ wQf,
    const float* __restrict__ gin_tab, const float* __restrict__ projP,
    const unsigned char* __restrict__ maskb, float* __restrict__ accum) {
  __shared__ float hsF[16][516];               // fp32 state
  __shared__ unsigned short hsB[16][520];      // bf16 state (16B-aligned frags)

  const int tid  = threadIdx.x;
  const int w    = tid >> 6;                   // wave 0..7
  const int lane = tid & 63;
  const int col0 = lane & 15;
  const int quad = lane >> 4;
  const int s0   = blockIdx.x << 4;            // 16 sequences per wg

  for (int it = tid; it < 16 * 128; it += 512) {
    int row = it >> 7, c4 = it & 127;
    float4 v = *(const float4*)(belief + ((size_t)(s0 + row) << 9) + (c4 << 2));
    *(float4*)&hsF[row][c4 << 2] = v;
    ushort4 o; o.x = f2b(v.x); o.y = f2b(v.y); o.z = f2b(v.z); o.w = f2b(v.w);
    *(ushort4*)&hsB[row][c4 << 2] = o;
  }

  const float b1v0 = b1[col0], b1v1 = b1[col0 + 16];
  const float w2v0 = W2[col0], w2v1 = W2[col0 + 16];
  const float b2v  = b2[0];
  const int gsl = s0 + col0;                   // this lane's A-row sequence
  const int tl  = gsl >> 3, nnl = gsl & 7;

  float sumP = 0.f, cntP = 0.f, sumN = 0.f, cntN = 0.f;
  bf16x8 a[16];

  __syncthreads();

  for (int j = 0; j <= KK; ++j) {
    #pragma unroll
    for (int kt = 0; kt < 16; ++kt)
      a[kt] = *(const bf16x8*)&hsB[col0][kt * 32 + quad * 8];

    if (j > 0 && w < 4) {                      // classifier + loss for step j-1
      const int jq = j - 1;
      f32x4 t0 = {0.f, 0.f, 0.f, 0.f}, t1 = {0.f, 0.f, 0.f, 0.f};
      const unsigned short* qp = wQf + (lane << 3);
      #pragma unroll
      for (int kt = 0; kt < 16; ++kt) {
        bf16x8 bq0 = *(const bf16x8*)(qp + ((size_t)kt << 9));
        bf16x8 bq1 = *(const bf16x8*)(qp + ((size_t)(16 + kt) << 9));
        t0 = MFMA16(a[kt], bq0, t0);
        t1 = MFMA16(a[kt], bq1, t1);
      }
      float wj = (jq == 0) ? 5.f : (jq == 1) ? 4.f : (jq < 4) ? 3.f : (jq < 8) ? 2.f : 1.f;
      #pragma unroll
      for (int r = 0; r < 4; ++r) {
        int m = (quad << 2) + r;
        int gs = s0 + m;
        int trow = gs >> 3, nn = gs & 7;
        unsigned mb = maskb[(trow << 7) + (jq << 3) + nn];   // uniform across quad
        if (mb) {
          int sp = gs + ((jq + 1) << 3);                     // partner row t+j+1
          float pp0 = projP[(sp << 5) + col0];
          float pp1 = projP[(sp << 5) + 16 + col0];
          int ni = neg_inds[sp];
          float pn0 = projP[(ni << 5) + col0];
          float pn1 = projP[(ni << 5) + 16 + col0];
          float a0v = t0[r] + b1v0, a1v = t1[r] + b1v1;
          float pl = fmaxf(a0v + pp0, 0.f) * w2v0 + fmaxf(a1v + pp1, 0.f) * w2v1;
          float nl = fmaxf(a0v + pn0, 0.f) * w2v0 + fmaxf(a1v + pn1, 0.f) * w2v1;
          #pragma unroll
          for (int d = 1; d < 16; d <<= 1) {
            pl += __shfl_xor(pl, d, 64);
            nl += __shfl_xor(nl, d, 64);
          }
          if (col0 == 0 && quad == w) {
            if (mb & 1u) {
              float x = -(pl + b2v);
              sumP += wj * (fmaxf(x, 0.f) + __logf(1.f + __expf(-fabsf(x))));
              cntP += 1.f;
            }
            if (mb & 2u) {
              float x = (nl + b2v);
              sumN += wj * (fmaxf(x, 0.f) + __logf(1.f + __expf(-fabsf(x))));
              cntN += 1.f;
            }
          }
        }
      }
    }
    if (j == KK) break;
    __syncthreads();                           // frag reads done before h updates

    // one-hot K-extension A fragment (gi for r,z + bias row)
    int tj = tl + j;
    int aidx = (tj < T_DIM) ? actions[(tj << 3) + nnl] : 7;
    bf16x8 aext = {0, 0, 0, 0, 0, 0, 0, 0};
    const short oneb = (short)0x3F80;
    if (quad == 0) {
      #pragma unroll
      for (int i = 0; i < 8; ++i) aext[i] = (aidx == i) ? oneb : (short)0;
    } else if (quad == 1) aext[0] = oneb;

    const unsigned short* wp = wBf + (((size_t)(w * 12 * 17)) << 9) + (lane << 3);
    for (int i = 0; i < 4; ++i) {
      const unsigned short* p = wp + (((size_t)(i * 51)) << 9);
      int nt = (w << 2) + i;
      int hcol = nt << 4;
      f32x4 accR = {0.f, 0.f, 0.f, 0.f}, accZ = accR, accN = accR;
      // depth-2 rolling prefetch, 3 independent coalesced 1KB streams
      bf16x8 bR0 = *(const bf16x8*)(p);
      bf16x8 bR1 = *(const bf16x8*)(p + (1 << 9));
      bf16x8 bZ0 = *(const bf16x8*)(p + (17 << 9));
      bf16x8 bZ1 = *(const bf16x8*)(p + (18 << 9));
      bf16x8 bN0 = *(const bf16x8*)(p + (34 << 9));
      bf16x8 bN1 = *(const bf16x8*)(p + (35 << 9));
      #pragma unroll
      for (int kt = 0; kt < 17; ++kt) {
        bf16x8 af = (kt < 16) ? a[kt] : aext;
        accR = MFMA16(af, bR0, accR);
        accZ = MFMA16(af, bZ0, accZ);
        accN = MFMA16(af, bN0, accN);
        bR0 = bR1; bZ0 = bZ1; bN0 = bN1;
        // prefetch kt+2 (overrun reads stay in wBf/pad, values unused)
        bR1 = *(const bf16x8*)(p + ((size_t)(kt + 2) << 9));
        bZ1 = *(const bf16x8*)(p + ((size_t)(17 + kt + 2) << 9));
        bN1 = *(const bf16x8*)(p + ((size_t)(34 + kt + 2) << 9));
      }

      #pragma unroll
      for (int r = 0; r < 4; ++r) {
        int m = (quad << 2) + r;
        int ai = __shfl(aidx, m, 64);
        float gin = gin_tab[(ai << 9) + hcol + col0];        // i_n
        float hp  = hsF[m][hcol + col0];
        float rg = 1.f / (1.f + __expf(-accR[r]));
        float zg = 1.f / (1.f + __expf(-accZ[r]));
        float pre = gin + rg * accN[r];
        float cand = 1.f - 2.f / (1.f + __expf(2.f * pre));  // tanh
        float hn = (1.f - zg) * cand + zg * hp;
        hsF[m][hcol + col0] = hn;
        hsB[m][hcol + col0] = f2b(hn);
      }
    }
    __syncthreads();                           // h_{j+1} visible to all waves
  }

  if (w < 4 && col0 == 0 && quad == w) {
    atomicAdd(&accum[0], sumP); atomicAdd(&accum[1], cntP);
    atomicAdd(&accum[2], sumN); atomicAdd(&accum[3], cntN);
  }
}

__global__ void fin(const float* __restrict__ accum, float* __restrict__ out) {
  out[0] = (accum[0] / fmaxf(accum[1], 1.f) + accum[2] / fmaxf(accum[3], 1.f)) * 0.1f;
}

extern "C" void kernel_launch(void* const* d_in, const int* in_sizes, int n_in,
                              void* d_out, int out_size, void* d_ws, size_t ws_size,
                              hipStream_t stream) {
  const float* vision  = (const float*)d_in[0];
  const float* belief  = (const float*)d_in[1];
  const int*   actions = (const int*)d_in[2];
  const int*   envz    = (const int*)d_in[3];
  const int*   negi    = (const int*)d_in[4];
  const float* emb     = (const float*)d_in[5];
  const float* W_ih    = (const float*)d_in[6];
  const float* W_hh    = (const float*)d_in[7];
  const float* b_ih    = (const float*)d_in[8];
  const float* b_hh    = (const float*)d_in[9];
  const float* W1      = (const float*)d_in[10];
  const float* b1      = (const float*)d_in[11];
  const float* W2      = (const float*)d_in[12];
  const float* b2      = (const float*)d_in[13];

  char* ws = (char*)d_ws;
  float*          accum   = (float*)(ws + 0);
  unsigned short* wBf     = (unsigned short*)(ws + 256);        // 1671168 B
  //                     pad 2048 B for prefetch overrun
  float*          gin_tab = (float*)(ws + 1673472);             // 16384 B
  float*          projP   = (float*)(ws + 1689856);             // 262144 B
  unsigned char*  maskb   = (unsigned char*)(ws + 1952000);     // 32768 B
  unsigned short* wQf     = (unsigned short*)(ws + 1984768);    // 32768 B

  prep_misc<<<336, 256, 0, stream>>>(emb, W_ih, b_ih, W1, vision, envz,
                                     gin_tab, projP, maskb, accum);
  prep_w<<<3328, 256, 0, stream>>>(W_hh, emb, W_ih, b_ih, b_hh, W1, wBf, wQf);
  gru_main<<<128, 512, 0, stream>>>(belief, actions, negi, b1, W2, b2,
                                    wBf, wQf, gin_tab, projP, maskb, accum);
  fin<<<1, 1, 0, stream>>>(accum, (float*)d_out);
}